// Round 7
// baseline (97.423 us; speedup 1.0000x reference)
//
#include <hip/hip_runtime.h>

#define N_OPS   60
#define BATCH   256
#define BOXD    12
#define SYMDIM  8
#define NBOX    32
#define NSYM    16
#define FD      1024
#define HD      2048
#define MAXSTK  20
#define MAXSYM  4
#define DZERO   (-1000000)
#define NB      64      // blocks, all co-resident (cooperative launch)
#define NTHR    256
#define NB2     32      // blocks active in L2 stages (1024 cols / 32)

// Cross-block data uses PLAIN loads/stores. Visibility across the 8
// non-coherent XCD L2s is provided at each barrier by a full release/acquire
// pair: release = buffer_wbl2 sc1 (flush XCD L2 to LLC) before arrival,
// acquire = buffer_inv sc1 after the spin. Barrier counters are monotonic
// (never reset): each call adds exactly NB per used barrier, so any
// multiple-of-NB start state is valid and graph replays are deterministic.
__device__ float    g_h[HD];            // current step's hidden vector
__device__ float    g_o[N_OPS][FD];     // finalized step outputs (post-tanh)
__device__ unsigned g_bar[2 * N_OPS];   // monotonic barrier counters

struct Params {
  const float* inputStacks;     // [32][256][12]
  const float* symmetryStacks;  // [16][256][8]
  const int*   ops;             // [60][256]
  const float* box_W;  const float* box_b;
  const float* adj_Wl; const float* adj_bl; const float* adj_Wr;
  const float* adj_W2; const float* adj_b2;
  const float* sym_Wl; const float* sym_bl; const float* sym_Wr; const float* sym_br;
  const float* sym_W2; const float* sym_b2;
  float* out;                   // [1024] fp32
};

static __device__ __forceinline__ int clampi(int v, int lo, int hi) {
  return v < lo ? lo : (v > hi ? hi : v);
}

// Value of descriptor d at element f. Boxes inline (12 MACs); step outputs
// via plain load from g_o (fresh after the acquire barrier).
static __device__ __forceinline__ float read_x(int d, int f, const Params& p) {
  if (d == DZERO) return 0.0f;
  if (d < 0) {
    int n = -d - 1;
    const float* x = p.inputStacks + (size_t)n * (BATCH * BOXD);  // batch 0
    float acc = p.box_b[f];
    #pragma unroll
    for (int k = 0; k < BOXD; ++k) acc += x[k] * p.box_W[(size_t)k * FD + f];
    return tanhf(acc);
  }
  return g_o[d][f];
}

// All-block barrier with full agent-scope release/acquire semantics.
// __syncthreads() drains every wave's vmem queue (stores reach the XCD L2);
// the RELEASE fence emits s_waitcnt + buffer_wbl2 sc1, writing the XCD's L2
// back to the LLC (covers all resident blocks' stores on this XCD); arrival
// counter is a relaxed agent fetch_add. After the spin, the ACQUIRE fence
// emits buffer_inv sc1 so subsequent plain loads miss to the LLC.
static __device__ __forceinline__ void gbarrier(int bi) {
  __syncthreads();
  if (threadIdx.x == 0) {
    __builtin_amdgcn_fence(__ATOMIC_RELEASE, "agent");
    unsigned v = __hip_atomic_fetch_add(&g_bar[bi], 1u,
                                        __ATOMIC_RELAXED, __HIP_MEMORY_SCOPE_AGENT);
    unsigned tgt = (v & ~(unsigned)(NB - 1)) + NB;
    while (__hip_atomic_load(&g_bar[bi],
                             __ATOMIC_RELAXED, __HIP_MEMORY_SCOPE_AGENT) < tgt)
      __builtin_amdgcn_s_sleep(2);
    __builtin_amdgcn_fence(__ATOMIC_ACQUIRE, "agent");
  }
  __syncthreads();
}

__global__ __launch_bounds__(NTHR) void grass_kernel(Params p) {
  __shared__ int s_ops[N_OPS];
  __shared__ int st_ty[N_OPS], st_a[N_OPS], st_b[N_OPS], st_c[N_OPS];
  __shared__ unsigned char st_live[N_OPS];
  __shared__ int sk_t[N_OPS], sk_ty[N_OPS], sk_a[N_OPS], sk_b[N_OPS], sk_c[N_OPS];
  __shared__ int s_nlive, s_root;
  __shared__ float s_x[2 * FD];        // S1 inputs (x, x2) / S2 hidden (2048)
  __shared__ float4 red[NTHR];
  __shared__ float s_stop[SYMDIM];

  const int tid = threadIdx.x, blk = blockIdx.x;

  // ---- Phase 0: every block redundantly runs the scalar sim (ops staged in
  // parallel); schedule stays in LDS — no global round-trip, no barrier.
  if (tid < N_OPS) s_ops[tid] = p.ops[tid * BATCH];  // batch 0
  __syncthreads();
  if (tid == 0) {
    int sd[MAXSTK], yd[MAXSYM];
    for (int i = 0; i < MAXSTK; ++i) sd[i] = DZERO;
    sd[0] = sd[1] = -1;                 // boxes_enc[0] == desc -(0+1)
    yd[0] = yd[1] = 0;                  // symmetryStacks row 0
    yd[2] = yd[3] = -1;                 // zero vector
    int sptr = 2, yptr = 2, bptr = NBOX - 1, qptr = NSYM - 1;
    for (int t = 0; t < N_OPS; ++t) {
      int op = s_ops[t];
      bool push = (op <= 1), madj = (op == 2), psym = (op == 1), msym = (op == 3);
      int pvd  = -(clampi(bptr, 0, NBOX - 1) + 1);
      int svd  = clampi(qptr, 0, NSYM - 1);
      int topd = sd[clampi(sptr - 1, 0, MAXSTK - 1)];
      int secd = sd[clampi(sptr - 2, 0, MAXSTK - 1)];
      int stpd = yd[clampi(yptr - 1, 0, MAXSYM - 1)];
      int wvd, wi, ty;
      if (push)      { wvd = pvd; wi = sptr;     ty = 0; }
      else if (madj) { wvd = t;   wi = sptr - 2; ty = 2; }
      else           { wvd = t;   wi = sptr - 1; ty = 3; }
      st_ty[t] = ty; st_a[t] = secd; st_b[t] = topd; st_c[t] = stpd; st_live[t] = 0;
      if (wi >= 0 && wi < MAXSTK) sd[wi] = wvd;
      if (psym) yd[clampi(yptr, 0, MAXSYM - 1)] = svd;
      sptr += push ? 1 : (madj ? -1 : 0);
      yptr += (psym ? 1 : 0) - (msym ? 1 : 0);
      bptr -= push ? 1 : 0;
      qptr -= psym ? 1 : 0;
    }
    int root = sd[clampi(sptr - 1, 0, MAXSTK - 1)];
    s_root = root;
    if (root >= 0) st_live[root] = 1;
    for (int t = N_OPS - 1; t >= 0; --t) {
      if (!st_live[t]) continue;
      if (st_ty[t] == 2) {
        if (st_a[t] >= 0) st_live[st_a[t]] = 1;
        if (st_b[t] >= 0) st_live[st_b[t]] = 1;
      } else {
        if (st_b[t] >= 0) st_live[st_b[t]] = 1;
      }
    }
    int nl = 0;
    for (int t = 0; t < N_OPS; ++t) {
      if (!st_live[t]) continue;
      sk_t[nl] = t; sk_ty[nl] = st_ty[t];
      sk_a[nl] = st_a[t]; sk_b[nl] = st_b[t]; sk_c[nl] = st_c[t];
      ++nl;
    }
    s_nlive = nl;
  }
  __syncthreads();

  if (s_nlive == 0) {                   // root is a box or zero
    if (blk == 0)
      for (int f = tid; f < FD; f += NTHR) p.out[f] = read_x(s_root, f, p);
    return;
  }

  const int cg = tid & 7, rs = tid >> 3;   // 8 float4-colgroups (32 cols) x 32 row-slices

  // ---- Live-step loop: per step, S1 (L1 GEMV) -> barrier -> S2 (L2 GEMV) -> barrier
  for (int k = 0; k < s_nlive; ++k) {
    const int t = sk_t[k], ty = sk_ty[k], a = sk_a[k], b = sk_b[k], c = sk_c[k];

    // S1: h[2048] = tanh(x@Wl (+ x2@Wr) + bl (+ br + stop@sym_Wr)).
    // 64 blocks x 32 cols; per-thread 32 rows of float4 (128 B-coalesced rows).
    {
      const int dl = (ty == 2) ? a : b;
      for (int i = tid; i < FD; i += NTHR) s_x[i] = read_x(dl, i, p);
      if (ty == 2)
        for (int i = tid; i < FD; i += NTHR) s_x[FD + i] = read_x(b, i, p);
      if (tid < SYMDIM)
        s_stop[tid] = (ty == 3 && c >= 0)
            ? p.symmetryStacks[(size_t)c * (BATCH * SYMDIM) + tid] : 0.0f;
      __syncthreads();

      const int col = blk * 32 + cg * 4;
      float4 acc = make_float4(0.f, 0.f, 0.f, 0.f);
      if (ty == 2) {
        #pragma unroll 8
        for (int r = 0; r < 32; ++r) {
          const int i = rs * 32 + r;
          const float4 wl = *(const float4*)(p.adj_Wl + (size_t)i * HD + col);
          const float4 wr = *(const float4*)(p.adj_Wr + (size_t)i * HD + col);
          const float xa = s_x[i], xb = s_x[FD + i];
          acc.x += xa * wl.x + xb * wr.x;  acc.y += xa * wl.y + xb * wr.y;
          acc.z += xa * wl.z + xb * wr.z;  acc.w += xa * wl.w + xb * wr.w;
        }
      } else {
        #pragma unroll 8
        for (int r = 0; r < 32; ++r) {
          const int i = rs * 32 + r;
          const float4 wl = *(const float4*)(p.sym_Wl + (size_t)i * HD + col);
          const float xa = s_x[i];
          acc.x += xa * wl.x;  acc.y += xa * wl.y;
          acc.z += xa * wl.z;  acc.w += xa * wl.w;
        }
      }
      red[tid] = acc;
      __syncthreads();
      if (rs == 0) {
        float4 s = red[cg];
        #pragma unroll
        for (int q = 1; q < 32; ++q) {
          const float4 v = red[q * 8 + cg];
          s.x += v.x; s.y += v.y; s.z += v.z; s.w += v.w;
        }
        float o[4] = {s.x, s.y, s.z, s.w};
        #pragma unroll
        for (int j = 0; j < 4; ++j) {
          float bias;
          if (ty == 2) {
            bias = p.adj_bl[col + j];
          } else {
            bias = p.sym_bl[col + j] + p.sym_br[col + j];
            #pragma unroll
            for (int q = 0; q < SYMDIM; ++q)
              bias += s_stop[q] * p.sym_Wr[(size_t)q * HD + col + j];
          }
          g_h[col + j] = tanhf(o[j] + bias);
        }
      }
    }
    gbarrier(2 * k);

    // S2: o[1024] = tanh(h@W2 + b2); 32 blocks x 32 cols; 64 rows/thread.
    if (blk < NB2) {
      for (int i = tid; i < HD; i += NTHR) s_x[i] = g_h[i];
      __syncthreads();

      const int col = blk * 32 + cg * 4;
      const float* W2 = (ty == 2) ? p.adj_W2 : p.sym_W2;
      float4 acc = make_float4(0.f, 0.f, 0.f, 0.f);
      #pragma unroll 8
      for (int r = 0; r < 64; ++r) {
        const int i = rs * 64 + r;
        const float4 w = *(const float4*)(W2 + (size_t)i * FD + col);
        const float h = s_x[i];
        acc.x += h * w.x;  acc.y += h * w.y;  acc.z += h * w.z;  acc.w += h * w.w;
      }
      red[tid] = acc;
      __syncthreads();
      if (rs == 0) {
        float4 s = red[cg];
        #pragma unroll
        for (int q = 1; q < 32; ++q) {
          const float4 v = red[q * 8 + cg];
          s.x += v.x; s.y += v.y; s.z += v.z; s.w += v.w;
        }
        const float* b2 = (ty == 2) ? p.adj_b2 : p.sym_b2;
        float o[4] = {s.x, s.y, s.z, s.w};
        #pragma unroll
        for (int j = 0; j < 4; ++j) {
          const float v = tanhf(o[j] + b2[col + j]);
          g_o[t][col + j] = v;
          if (t == s_root) p.out[col + j] = v;   // host-visible at kernel end
        }
      }
    }
    if (k + 1 < s_nlive) gbarrier(2 * k + 1);    // no consumer after last S2
  }
}

extern "C" void kernel_launch(void* const* d_in, const int* in_sizes, int n_in,
                              void* d_out, int out_size, void* d_ws, size_t ws_size,
                              hipStream_t stream) {
  Params p;
  p.inputStacks    = (const float*)d_in[0];
  p.symmetryStacks = (const float*)d_in[1];
  p.ops            = (const int*)d_in[2];
  p.box_W  = (const float*)d_in[3];
  p.box_b  = (const float*)d_in[4];
  p.adj_Wl = (const float*)d_in[5];
  p.adj_bl = (const float*)d_in[6];
  p.adj_Wr = (const float*)d_in[7];
  p.adj_W2 = (const float*)d_in[8];
  p.adj_b2 = (const float*)d_in[9];
  p.sym_Wl = (const float*)d_in[10];
  p.sym_bl = (const float*)d_in[11];
  p.sym_Wr = (const float*)d_in[12];
  p.sym_br = (const float*)d_in[13];
  p.sym_W2 = (const float*)d_in[14];
  p.sym_b2 = (const float*)d_in[15];
  p.out    = (float*)d_out;

  void* args[] = { &p };
  (void)hipLaunchCooperativeKernel((const void*)grass_kernel,
                                   dim3(NB), dim3(NTHR), args, 0, stream);
}

// Round 8
// 78.617 us; speedup vs baseline: 1.2392x; 1.2392x over previous
//
#include <hip/hip_runtime.h>

#define N_OPS   60
#define BATCH   256
#define BOXD    12
#define SYMDIM  8
#define NBOX    32
#define NSYM    16
#define FD      1024
#define HD      2048
#define MAXSTK  20
#define MAXSYM  4
#define DZERO   (-1000000)
#define NB      256     // blocks, all co-resident (cooperative launch), 1/CU
#define NTHR    256
#define GRPS    8       // barrier tree: 8 groups x 32 blocks
#define NBAR    (2 * N_OPS)

// Coherence protocol (proven pieces only):
//  - All cross-block DATA (g_p1/g_p2) is written with relaxed AGENT-scope
//    atomicExch: agent atomics execute at the LLC (cross-XCD coherent point),
//    so dirty data never sits in a private XCD L2 -> no release wbl2 needed.
//  - Readers get freshness from the barrier's ACQUIRE fence (buffer_inv sc1),
//    the same acquire R7 validated.
//  - Barrier counters are monotonic (never reset): per call each group adds
//    exactly 32, root adds 8, epoch adds 1; a block's target epoch is derived
//    from its own arrival ticket, so graph replays are deterministic and
//    stragglers can't deadlock across replays.
__device__ unsigned g_grp[NBAR][GRPS][32];   // [..][..][0] used; 128 B padding
__device__ unsigned g_rootc[NBAR][32];
__device__ unsigned g_epoch[NBAR][32];
__device__ float    g_p1[4][HD];             // L1 split-K partials (per step, transient)
__device__ float    g_p2[N_OPS][8][FD];      // L2 split-K partials, per live step

struct Params {
  const float* inputStacks;     // [32][256][12]
  const float* symmetryStacks;  // [16][256][8]
  const int*   ops;             // [60][256]
  const float* box_W;  const float* box_b;
  const float* adj_Wl; const float* adj_bl; const float* adj_Wr;
  const float* adj_W2; const float* adj_b2;
  const float* sym_Wl; const float* sym_bl; const float* sym_Wr; const float* sym_br;
  const float* sym_W2; const float* sym_b2;
  float* out;                   // [1024] fp32
};

static __device__ __forceinline__ int clampi(int v, int lo, int hi) {
  return v < lo ? lo : (v > hi ? hi : v);
}

// LLC-coherent 8-byte store (relaxed agent atomic exchange -> performed at LLC).
static __device__ __forceinline__ void llc_store2(float* dst, float a, float b) {
  union { float f[2]; unsigned long long u; } v;
  v.f[0] = a; v.f[1] = b;
  (void)__hip_atomic_exchange((unsigned long long*)dst, v.u,
                              __ATOMIC_RELAXED, __HIP_MEMORY_SCOPE_AGENT);
}

// Tree barrier: 32-wide group arrival -> root -> epoch bump; spin on epoch.
// Acquire fence (buffer_inv) after the spin makes all LLC data visible to
// subsequent plain loads.
static __device__ __forceinline__ void gbarrier(int bi) {
  __syncthreads();   // all waves drain vmem (stores/atomics complete) before arrival
  if (threadIdx.x == 0) {
    const int g = blockIdx.x >> 5;
    unsigned v = __hip_atomic_fetch_add(&g_grp[bi][g][0], 1u,
                                        __ATOMIC_RELAXED, __HIP_MEMORY_SCOPE_AGENT);
    const unsigned target = (v >> 5) + 1;   // this call's epoch index + 1
    if ((v & 31u) == 31u) {
      unsigned u = __hip_atomic_fetch_add(&g_rootc[bi][0], 1u,
                                          __ATOMIC_RELAXED, __HIP_MEMORY_SCOPE_AGENT);
      if ((u & 7u) == 7u)
        (void)__hip_atomic_fetch_add(&g_epoch[bi][0], 1u,
                                     __ATOMIC_RELAXED, __HIP_MEMORY_SCOPE_AGENT);
    }
    while (__hip_atomic_load(&g_epoch[bi][0],
                             __ATOMIC_RELAXED, __HIP_MEMORY_SCOPE_AGENT) < target)
      __builtin_amdgcn_s_sleep(2);
    __builtin_amdgcn_fence(__ATOMIC_ACQUIRE, "agent");
  }
  __syncthreads();
}

// Value of descriptor d at element f. Boxes inline (12 MACs); step outputs
// reconstructed from that step's 8 L2 partials (+bias, tanh).
static __device__ __forceinline__ float read_x(int d, int f, const Params& p,
                                               const int* st_ty) {
  if (d == DZERO) return 0.0f;
  if (d < 0) {
    int n = -d - 1;
    const float* x = p.inputStacks + (size_t)n * (BATCH * BOXD);  // batch 0
    float acc = p.box_b[f];
    #pragma unroll
    for (int k = 0; k < BOXD; ++k) acc += x[k] * p.box_W[(size_t)k * FD + f];
    return tanhf(acc);
  }
  float acc = ((st_ty[d] == 2) ? p.adj_b2 : p.sym_b2)[f];
  #pragma unroll
  for (int q = 0; q < 8; ++q) acc += g_p2[d][q][f];
  return tanhf(acc);
}

__global__ __launch_bounds__(NTHR) void grass_kernel(Params p) {
  __shared__ int s_ops[N_OPS];
  __shared__ int st_ty[N_OPS], st_a[N_OPS], st_b[N_OPS], st_c[N_OPS];
  __shared__ unsigned char st_live[N_OPS];
  __shared__ int sk_t[N_OPS], sk_ty[N_OPS], sk_a[N_OPS], sk_b[N_OPS], sk_c[N_OPS];
  __shared__ int s_nlive, s_root;
  __shared__ float s_x[NTHR], s_x2[NTHR];   // staged 256-row input/h slices
  __shared__ float4 red[NTHR];

  const int tid = threadIdx.x, blk = blockIdx.x;

  // ---- Phase 0: every block redundantly runs the scalar sim (ops staged in
  // parallel); schedule stays in LDS — no global round-trip, no barrier.
  if (tid < N_OPS) s_ops[tid] = p.ops[tid * BATCH];  // batch 0
  __syncthreads();
  if (tid == 0) {
    int sd[MAXSTK], yd[MAXSYM];
    for (int i = 0; i < MAXSTK; ++i) sd[i] = DZERO;
    sd[0] = sd[1] = -1;                 // boxes_enc[0] == desc -(0+1)
    yd[0] = yd[1] = 0;                  // symmetryStacks row 0
    yd[2] = yd[3] = -1;                 // zero vector
    int sptr = 2, yptr = 2, bptr = NBOX - 1, qptr = NSYM - 1;
    for (int t = 0; t < N_OPS; ++t) {
      int op = s_ops[t];
      bool push = (op <= 1), madj = (op == 2), psym = (op == 1), msym = (op == 3);
      int pvd  = -(clampi(bptr, 0, NBOX - 1) + 1);
      int svd  = clampi(qptr, 0, NSYM - 1);
      int topd = sd[clampi(sptr - 1, 0, MAXSTK - 1)];
      int secd = sd[clampi(sptr - 2, 0, MAXSTK - 1)];
      int stpd = yd[clampi(yptr - 1, 0, MAXSYM - 1)];
      int wvd, wi, ty;
      if (push)      { wvd = pvd; wi = sptr;     ty = 0; }
      else if (madj) { wvd = t;   wi = sptr - 2; ty = 2; }
      else           { wvd = t;   wi = sptr - 1; ty = 3; }
      st_ty[t] = ty; st_a[t] = secd; st_b[t] = topd; st_c[t] = stpd; st_live[t] = 0;
      if (wi >= 0 && wi < MAXSTK) sd[wi] = wvd;
      if (psym) yd[clampi(yptr, 0, MAXSYM - 1)] = svd;
      sptr += push ? 1 : (madj ? -1 : 0);
      yptr += (psym ? 1 : 0) - (msym ? 1 : 0);
      bptr -= push ? 1 : 0;
      qptr -= psym ? 1 : 0;
    }
    int root = sd[clampi(sptr - 1, 0, MAXSTK - 1)];
    s_root = root;
    if (root >= 0) st_live[root] = 1;
    for (int t = N_OPS - 1; t >= 0; --t) {
      if (!st_live[t]) continue;
      if (st_ty[t] == 2) {
        if (st_a[t] >= 0) st_live[st_a[t]] = 1;
        if (st_b[t] >= 0) st_live[st_b[t]] = 1;
      } else {
        if (st_b[t] >= 0) st_live[st_b[t]] = 1;
      }
    }
    int nl = 0;
    for (int t = 0; t < N_OPS; ++t) {
      if (!st_live[t]) continue;
      sk_t[nl] = t; sk_ty[nl] = st_ty[t];
      sk_a[nl] = st_a[t]; sk_b[nl] = st_b[t]; sk_c[nl] = st_c[t];
      ++nl;
    }
    s_nlive = nl;
  }
  __syncthreads();

  if (s_nlive == 0) {                   // root is a box or zero
    if (blk == 0)
      for (int f = tid; f < FD; f += NTHR) p.out[f] = read_x(s_root, f, p, st_ty);
    return;
  }

  const int cg = tid & 7, rs = tid >> 3;   // 8 float4-colgroups (32 cols) x 32 row-slices

  // ---- Live-step loop: S1 (L1 split-K) -> bar -> S2 (L2 split-K) -> bar
  for (int k = 0; k < s_nlive; ++k) {
    const int t = sk_t[k], ty = sk_ty[k], a = sk_a[k], b = sk_b[k], c = sk_c[k];

    // S1: 256 blocks = 64 col-tiles(32) x 4 k-tiles(256 rows of FD).
    // g_p1[kt][col] = sum over k-tile of x[i]*Wl[i][col] (+ x2[i]*Wr[i][col]).
    {
      const int ct = blk >> 2, kt = blk & 3;
      const int col0 = ct * 32, k0 = kt * 256;
      const int dl = (ty == 2) ? a : b;
      s_x[tid] = read_x(dl, k0 + tid, p, st_ty);
      if (ty == 2) s_x2[tid] = read_x(b, k0 + tid, p, st_ty);
      __syncthreads();

      const int col = col0 + cg * 4;
      float4 acc = make_float4(0.f, 0.f, 0.f, 0.f);
      if (ty == 2) {
        #pragma unroll
        for (int r = 0; r < 8; ++r) {
          const int l = rs * 8 + r;
          const size_t i = (size_t)(k0 + l);
          const float4 wl = *(const float4*)(p.adj_Wl + i * HD + col);
          const float4 wr = *(const float4*)(p.adj_Wr + i * HD + col);
          const float xa = s_x[l], xb = s_x2[l];
          acc.x += xa * wl.x + xb * wr.x;  acc.y += xa * wl.y + xb * wr.y;
          acc.z += xa * wl.z + xb * wr.z;  acc.w += xa * wl.w + xb * wr.w;
        }
      } else {
        #pragma unroll
        for (int r = 0; r < 8; ++r) {
          const int l = rs * 8 + r;
          const size_t i = (size_t)(k0 + l);
          const float4 wl = *(const float4*)(p.sym_Wl + i * HD + col);
          const float xa = s_x[l];
          acc.x += xa * wl.x;  acc.y += xa * wl.y;
          acc.z += xa * wl.z;  acc.w += xa * wl.w;
        }
      }
      red[tid] = acc;
      __syncthreads();
      if (rs == 0) {                    // tid 0..7: reduce 32 slices, LLC-store
        float4 s = red[cg];
        #pragma unroll
        for (int q = 1; q < 32; ++q) {
          const float4 v = red[q * 8 + cg];
          s.x += v.x; s.y += v.y; s.z += v.z; s.w += v.w;
        }
        llc_store2(&g_p1[kt][col], s.x, s.y);
        llc_store2(&g_p1[kt][col + 2], s.z, s.w);
      }
    }
    gbarrier(2 * k);

    // S2: 256 blocks = 32 col-tiles(32) x 8 k-tiles(256 rows of HD).
    // h[i] = tanh(bias(i) + sum_q g_p1[q][i]); partials -> g_p2[t][kt][col].
    {
      const int ct = blk >> 3, kt = blk & 7;
      const int col0 = ct * 32, k0 = kt * 256;
      {
        const int i = k0 + tid;
        float acc;
        if (ty == 2) {
          acc = p.adj_bl[i];
        } else {
          acc = p.sym_bl[i] + p.sym_br[i];
          if (c >= 0) {
            const float* stop = p.symmetryStacks + (size_t)c * (BATCH * SYMDIM);
            #pragma unroll
            for (int q = 0; q < SYMDIM; ++q)
              acc += stop[q] * p.sym_Wr[(size_t)q * HD + i];
          }
        }
        #pragma unroll
        for (int q = 0; q < 4; ++q) acc += g_p1[q][i];
        s_x[tid] = tanhf(acc);
      }
      __syncthreads();

      const int col = col0 + cg * 4;
      const float* W2 = (ty == 2) ? p.adj_W2 : p.sym_W2;
      float4 acc = make_float4(0.f, 0.f, 0.f, 0.f);
      #pragma unroll
      for (int r = 0; r < 8; ++r) {
        const int l = rs * 8 + r;
        const size_t i = (size_t)(k0 + l);
        const float4 w = *(const float4*)(W2 + i * FD + col);
        const float h = s_x[l];
        acc.x += h * w.x;  acc.y += h * w.y;  acc.z += h * w.z;  acc.w += h * w.w;
      }
      red[tid] = acc;
      __syncthreads();
      if (rs == 0) {
        float4 s = red[cg];
        #pragma unroll
        for (int q = 1; q < 32; ++q) {
          const float4 v = red[q * 8 + cg];
          s.x += v.x; s.y += v.y; s.z += v.z; s.w += v.w;
        }
        llc_store2(&g_p2[t][kt][col], s.x, s.y);
        llc_store2(&g_p2[t][kt][col + 2], s.z, s.w);
      }
      __syncthreads();                  // protect s_x before next S1 reuses it
    }
    gbarrier(2 * k + 1);
  }

  // ---- Out: root == last live step (liveness only marks ancestors of root).
  if (blk < 4) {
    const int f = blk * NTHR + tid;
    float acc = ((st_ty[s_root] == 2) ? p.adj_b2 : p.sym_b2)[f];
    #pragma unroll
    for (int q = 0; q < 8; ++q) acc += g_p2[s_root][q][f];
    p.out[f] = tanhf(acc);
  }
}

extern "C" void kernel_launch(void* const* d_in, const int* in_sizes, int n_in,
                              void* d_out, int out_size, void* d_ws, size_t ws_size,
                              hipStream_t stream) {
  Params p;
  p.inputStacks    = (const float*)d_in[0];
  p.symmetryStacks = (const float*)d_in[1];
  p.ops            = (const int*)d_in[2];
  p.box_W  = (const float*)d_in[3];
  p.box_b  = (const float*)d_in[4];
  p.adj_Wl = (const float*)d_in[5];
  p.adj_bl = (const float*)d_in[6];
  p.adj_Wr = (const float*)d_in[7];
  p.adj_W2 = (const float*)d_in[8];
  p.adj_b2 = (const float*)d_in[9];
  p.sym_Wl = (const float*)d_in[10];
  p.sym_bl = (const float*)d_in[11];
  p.sym_Wr = (const float*)d_in[12];
  p.sym_br = (const float*)d_in[13];
  p.sym_W2 = (const float*)d_in[14];
  p.sym_b2 = (const float*)d_in[15];
  p.out    = (float*)d_out;

  void* args[] = { &p };
  (void)hipLaunchCooperativeKernel((const void*)grass_kernel,
                                   dim3(NB), dim3(NTHR), args, 0, stream);
}